// Round 1
// baseline (257.249 us; speedup 1.0000x reference)
//
#include <hip/hip_runtime.h>
#include <math.h>

#define NNODES 50000
#define NEDGE  800000
#define NG     3
#define D      128
#define GE     (NG*NEDGE)            // 2,400,000 combined edges
#define NBUK   768                   // buckets: bucket(r) = r*48/3125, 65-66 rows each -> exactly 3 blocks/CU
#define GEMMB  782                   // gemm blocks of 64 rows (independent of bucketing)
#define CH     4096                  // edges per k_bin block
#define NBLK   ((GE + CH - 1) / CH)  // 586
#define OS     (NBUK + 1)            // 769, off1 row stride
#define CAP    4096                  // sorted-record cap per bucket (mean 3168 + 8-pad <= ~3830 worst)

typedef __attribute__((ext_vector_type(8))) short bf16x8;
typedef __attribute__((ext_vector_type(4))) float f32x4;

// fp32 -> bf16 round-to-nearest-even (no NaN inputs here)
__device__ __forceinline__ unsigned short f2bf(float f) {
    unsigned u = __float_as_uint(f);
    return (unsigned short)((u + 0x7fffu + ((u >> 16) & 1u)) >> 16);
}

// bucket of row r: floor(r*768/50000) = floor(r*48/3125); exact for r < 67650
__device__ __forceinline__ int bucket_of(unsigned r) {
    return (int)((r * 48u) / 3125u);
}

// ---------------------------------------------------------------------------
// K0: swizzle W (fp32 [128][128], row=out) into bf16 MFMA B-fragment order.
// ---------------------------------------------------------------------------
__global__ void k_wprep(const float* __restrict__ W, uint4* __restrict__ Wf) {
    const int t = threadIdx.x;   // 256 threads, 1 block
    for (int i = t; i < 2048; i += 256) {
        const int nt   = i >> 8;         // 0..7
        const int kc   = (i >> 6) & 3;   // 0..3
        const int lane = i & 63;
        const int n  = nt * 16 + (lane & 15);
        const int k0 = kc * 32 + (lane >> 4) * 8;
        const float* src = W + (size_t)n * 128 + k0;
        unsigned u0 = (unsigned)f2bf(src[0]) | ((unsigned)f2bf(src[1]) << 16);
        unsigned u1 = (unsigned)f2bf(src[2]) | ((unsigned)f2bf(src[3]) << 16);
        unsigned u2 = (unsigned)f2bf(src[4]) | ((unsigned)f2bf(src[5]) << 16);
        unsigned u3 = (unsigned)f2bf(src[6]) | ((unsigned)f2bf(src[7]) << 16);
        Wf[i] = make_uint4(u0, u1, u2, u3);
    }
}

// ---------------------------------------------------------------------------
// K1: h = X @ W^T via bf16 MFMA 16x16x32 (unchanged, proven).
// ---------------------------------------------------------------------------
__global__ __launch_bounds__(256) void k_gemm(const float* __restrict__ X,
                                              const uint4* __restrict__ Wf,
                                              unsigned short* __restrict__ hb16) {
    __shared__ uint4 Wl[2048];   // 32KB
    const int t = threadIdx.x;
#pragma unroll
    for (int j = 0; j < 8; ++j) Wl[t + j * 256] = Wf[t + j * 256];
    __syncthreads();

    const int w    = t >> 6;
    const int lane = t & 63;
    const int q    = lane >> 4;
    const int ml   = lane & 15;
    const int m0   = blockIdx.x * 64 + w * 16;

    int xr = m0 + ml; if (xr >= NNODES) xr = NNODES - 1;   // clamp (stores guarded)
    const float* xrow = X + (size_t)xr * 128;

    bf16x8 xf[4];
#pragma unroll
    for (int kc = 0; kc < 4; ++kc) {
        const int k0 = kc * 32 + q * 8;
        float4 a = *(const float4*)(xrow + k0);
        float4 b = *(const float4*)(xrow + k0 + 4);
        bf16x8 v;
        v[0] = (short)f2bf(a.x); v[1] = (short)f2bf(a.y);
        v[2] = (short)f2bf(a.z); v[3] = (short)f2bf(a.w);
        v[4] = (short)f2bf(b.x); v[5] = (short)f2bf(b.y);
        v[6] = (short)f2bf(b.z); v[7] = (short)f2bf(b.w);
        xf[kc] = v;
    }

#pragma unroll
    for (int nt = 0; nt < 8; ++nt) {
        f32x4 acc = {0.f, 0.f, 0.f, 0.f};
#pragma unroll
        for (int kc = 0; kc < 4; ++kc) {
            const bf16x8 wf = *(const bf16x8*)&Wl[(nt * 4 + kc) * 64 + lane];
            acc = __builtin_amdgcn_mfma_f32_16x16x32_bf16(xf[kc], wf, acc, 0, 0, 0);
        }
#pragma unroll
        for (int r = 0; r < 4; ++r) {
            const int row = m0 + q * 4 + r;
            if (row < NNODES)
                hb16[(size_t)row * 128 + nt * 16 + ml] = f2bf(acc[r]);
        }
    }
}

// ---------------------------------------------------------------------------
// K2: per-block bucket binning into 768 division-mapped buckets. Same r8
// structure: single global read pass, rank = atomicAdd return, pass 2 pure
// base+rank stores.
// ---------------------------------------------------------------------------
__global__ __launch_bounds__(256) void k_bin(const int* __restrict__ rows,
                                             const int* __restrict__ cols,
                                             const float* __restrict__ vals,
                                             const float* __restrict__ alpha,
                                             uint2* __restrict__ out1,
                                             int* __restrict__ off1) {
    __shared__ uint2 stg[CH];              // 32768 B
    __shared__ unsigned short rnk[CH];     //  8192 B
    __shared__ int sA[1024];               //  4096 B
    const int t   = threadIdx.x;
    const int blk = blockIdx.x;
    const int start = blk * CH;
    const int end   = (start + CH < GE) ? (start + CH) : GE;

    const float g0 = 1.0f / (1.0f + __expf(-alpha[0]));
    const float g1 = 1.0f / (1.0f + __expf(-alpha[1]));
    const float g2 = 1.0f / (1.0f + __expf(-alpha[2]));

#pragma unroll
    for (int j = 0; j < 4; ++j) sA[t + j * 256] = 0;
    __syncthreads();

    // pass 1: read globals once, pack record into LDS, histogram + rank
    for (int idx = start + t, k = t; idx < end; idx += 256, k += 256) {
        const int r = rows[idx];
        const int c = cols[idx];
        const float v = vals[idx];
        const float gv = v * (idx < NEDGE ? g0 : (idx < 2 * NEDGE ? g1 : g2));
        uint2 rec;
        rec.x = ((unsigned)r << 16) | (unsigned)c;   // both < 65536
        rec.y = __float_as_uint(gv);
        stg[k] = rec;
        rnk[k] = (unsigned short)atomicAdd(&sA[bucket_of((unsigned)r)], 1);
    }
    __syncthreads();

    // in-place inclusive scan over 1024 (two barriers per step)
    for (int off = 1; off < 1024; off <<= 1) {
        int v[4];
#pragma unroll
        for (int j = 0; j < 4; ++j) {
            const int i = t + j * 256;
            v[j] = sA[i] + ((i >= off) ? sA[i - off] : 0);
        }
        __syncthreads();
#pragma unroll
        for (int j = 0; j < 4; ++j) sA[t + j * 256] = v[j];
        __syncthreads();
    }

    // off1 = exclusive offsets
    for (int b = t; b < NBUK; b += 256)
        off1[(size_t)blk * OS + b] = b ? sA[b - 1] : 0;
    if (t == 0) off1[(size_t)blk * OS + NBUK] = sA[NBUK - 1];

    // pass 2: position = base[bucket] + rank, grouped write, no atomics
    for (int idx = start + t, k = t; idx < end; idx += 256, k += 256) {
        const uint2 rec = stg[k];
        const int b = bucket_of(rec.x >> 16);
        const int pos = (b ? sA[b - 1] : 0) + (int)rnk[k];
        out1[(size_t)blk * CH + pos] = rec;
    }
}

// ---------------------------------------------------------------------------
// K3: one block (512 thr = 8 waves) per 65/66-row bucket. 768 blocks = exactly
// 3/CU (fixes the 4-unit makespan tail seen at 782 blocks / Occ 55%).
// Records scattered DIRECTLY into row-sorted colS/valS arrays (order within a
// row is irrelevant for a sum) -> gather loop has zero LDS indirection:
// one aligned ds_read_b128 yields 8 cols, then 8 independent coalesced 256B
// global gathers. Row bases padded to 8 for 16B-aligned vector LDS reads.
// ---------------------------------------------------------------------------
__global__ __launch_bounds__(512) void k_agg3(const unsigned* __restrict__ hbits,
                                              const uint2* __restrict__ out1,
                                              const int* __restrict__ off1,
                                              float* __restrict__ out) {
    __shared__ __align__(16) unsigned short colS[CAP];   //  8192 B
    __shared__ __align__(16) float          valS[CAP];   // 16384 B
    __shared__ int rh[72], rbase[72], rcur[72];
    __shared__ int sS[128];
    const int t = threadIdx.x;
    const int b = blockIdx.x;

    // bucket row range: [ceil(b*3125/48), ceil((b+1)*3125/48))
    const int sstart = (b * 3125 + 47) / 48;
    const int send   = ((b + 1) * 3125 + 47) / 48;
    const int width  = send - sstart;                    // 65 or 66

    if (t < 72) rh[t] = 0;

    // segment ranges (thread t covers k_bin blocks t and t+512)
    const int s0 = off1[(size_t)t * OS + b];
    const int e0 = off1[(size_t)t * OS + b + 1];
    int s1 = 0, e1 = 0;
    if (t + 512 < NBLK) {
        s1 = off1[(size_t)(t + 512) * OS + b];
        e1 = off1[(size_t)(t + 512) * OS + b + 1];
    }
    __syncthreads();

    // P1: histogram rows (records discarded; re-read in P3 is L2-hot)
    {
        const uint2* seg = out1 + (size_t)t * CH;
        for (int i = s0; i < e0; ++i)
            atomicAdd(&rh[(int)(seg[i].x >> 16) - sstart], 1);
        const uint2* seg2 = out1 + (size_t)(t + 512) * CH;
        for (int i = s1; i < e1; ++i)
            atomicAdd(&rh[(int)(seg2[i].x >> 16) - sstart], 1);
    }
    __syncthreads();

    // P2: scan of 8-padded counts -> 8-aligned row bases
    if (t < 128) sS[t] = (t < width) ? ((rh[t] + 7) & ~7) : 0;
    __syncthreads();
    for (int off = 1; off < 128; off <<= 1) {
        int v = 0;
        if (t < 128) v = sS[t] + ((t >= off) ? sS[t - off] : 0);
        __syncthreads();
        if (t < 128) sS[t] = v;
        __syncthreads();
    }
    if (t < width) {
        const int rb = sS[t] - ((rh[t] + 7) & ~7);
        rbase[t] = rb;
        rcur[t]  = rb;
    }
    __syncthreads();

    // P3: re-read segments, scatter straight into sorted position
    {
        const uint2* seg = out1 + (size_t)t * CH;
        for (int i = s0; i < e0; ++i) {
            const uint2 rec = seg[i];
            const int lr  = (int)(rec.x >> 16) - sstart;
            const int pos = atomicAdd(&rcur[lr], 1);
            if (pos < CAP) {
                colS[pos] = (unsigned short)(rec.x & 0xffffu);
                valS[pos] = __uint_as_float(rec.y);
            }
        }
        const uint2* seg2 = out1 + (size_t)(t + 512) * CH;
        for (int i = s1; i < e1; ++i) {
            const uint2 rec = seg2[i];
            const int lr  = (int)(rec.x >> 16) - sstart;
            const int pos = atomicAdd(&rcur[lr], 1);
            if (pos < CAP) {
                colS[pos] = (unsigned short)(rec.x & 0xffffu);
                valS[pos] = __uint_as_float(rec.y);
            }
        }
    }
    __syncthreads();

    // P4: gather. Wave w owns rows lr = w, w+8, ... (8-9 rows).
    const int w    = t >> 6;
    const int lane = t & 63;
    for (int lr = w; lr < width; lr += 8) {
        const int s = rbase[lr];
        int cnt = rh[lr];
        if (s + cnt > CAP) cnt = (CAP > s) ? (CAP - s) : 0;   // overflow guard
        float2 acc = make_float2(0.f, 0.f);
        int i = 0;
        for (; i + 8 <= cnt; i += 8) {
            const uint4  cv = *(const uint4*)&colS[s + i];     // 8 cols, 16B-aligned
            const float4 va = *(const float4*)&valS[s + i];
            const float4 vb = *(const float4*)&valS[s + i + 4];
            unsigned hb[8];
            hb[0] = hbits[(size_t)(cv.x & 0xffffu) * 64 + lane];
            hb[1] = hbits[(size_t)(cv.x >> 16)     * 64 + lane];
            hb[2] = hbits[(size_t)(cv.y & 0xffffu) * 64 + lane];
            hb[3] = hbits[(size_t)(cv.y >> 16)     * 64 + lane];
            hb[4] = hbits[(size_t)(cv.z & 0xffffu) * 64 + lane];
            hb[5] = hbits[(size_t)(cv.z >> 16)     * 64 + lane];
            hb[6] = hbits[(size_t)(cv.w & 0xffffu) * 64 + lane];
            hb[7] = hbits[(size_t)(cv.w >> 16)     * 64 + lane];
            const float vv[8] = {va.x, va.y, va.z, va.w, vb.x, vb.y, vb.z, vb.w};
#pragma unroll
            for (int j = 0; j < 8; ++j) {
                acc.x += vv[j] * __uint_as_float(hb[j] << 16);
                acc.y += vv[j] * __uint_as_float(hb[j] & 0xffff0000u);
            }
        }
        for (; i < cnt; ++i) {
            const unsigned c   = colS[s + i];
            const float    v   = valS[s + i];
            const unsigned hbv = hbits[(size_t)c * 64 + lane];
            acc.x += v * __uint_as_float(hbv << 16);
            acc.y += v * __uint_as_float(hbv & 0xffff0000u);
        }
        const int row = sstart + lr;
        ((float2*)out)[(size_t)row * 64 + lane] = acc;
    }
}

extern "C" void kernel_launch(void* const* d_in, const int* in_sizes, int n_in,
                              void* d_out, int out_size, void* d_ws, size_t ws_size,
                              hipStream_t stream) {
    const float* X     = (const float*)d_in[0];
    const float* W     = (const float*)d_in[1];
    const float* alpha = (const float*)d_in[2];
    const int*   rows  = (const int*)d_in[3];
    const int*   cols  = (const int*)d_in[4];
    const float* vals  = (const float*)d_in[5];
    float* out = (float*)d_out;

    // workspace layout
    char* ws = (char*)d_ws;
    unsigned*       hbits = (unsigned*)(ws + 0);            // 12,800,000 B
    unsigned short* hb16  = (unsigned short*)(ws + 0);      // same bytes, u16 view
    uint2*          out1  = (uint2*)(ws + 12800000);        // 19,202,048 B
    int*            off1  = (int*)  (ws + 32002048);        // 586*769*4 = 1,802,536 B
    uint4*          Wf    = (uint4*)(ws + 33837408);        //     32,768 B
    // total: 33,870,176 B

    hipLaunchKernelGGL(k_wprep, dim3(1), dim3(256), 0, stream, W, Wf);
    hipLaunchKernelGGL(k_gemm, dim3(GEMMB), dim3(256), 0, stream, X, Wf, hb16);
    hipLaunchKernelGGL(k_bin, dim3(NBLK), dim3(256), 0, stream,
                       rows, cols, vals, alpha, out1, off1);
    hipLaunchKernelGGL(k_agg3, dim3(NBUK), dim3(512), 0, stream,
                       hbits, out1, off1, out);
}

// Round 2
// 220.894 us; speedup vs baseline: 1.1646x; 1.1646x over previous
//
#include <hip/hip_runtime.h>
#include <math.h>

#define NNODES 50000
#define NEDGE  800000
#define NG     3
#define GE     (NG*NEDGE)            // 2,400,000 combined edges
#define NBUK   1536                  // row buckets: bucket(r) = r*96/3125 -> 32/33 rows each
#define OS     (NBUK + 1)            // 1537, off1 row stride
#define CH     4800                  // edges per bin block; 500*4800 == GE exactly
#define NBLK   (GE / CH)             // 500  (<= 512: one segment per k_agg thread)
#define GBLK   391                   // gemm sub-grid blocks of 128 rows (391*128 = 50048)
#define FGRID  (GBLK + NBLK)         // 891 fused front-kernel blocks
#define STGCAP 1920                  // raw record cap per bucket (mean 1584, sigma 40; 8.4-sigma margin)
#define SCAP   2176                  // sorted cap: STGCAP + 33*7 = 2151 worst -> never overflows

typedef __attribute__((ext_vector_type(8))) short bf16x8;
typedef __attribute__((ext_vector_type(4))) float f32x4;

// fp32 -> bf16 round-to-nearest-even (no NaN inputs here)
__device__ __forceinline__ unsigned short f2bf(float f) {
    unsigned u = __float_as_uint(f);
    return (unsigned short)((u + 0x7fffu + ((u >> 16) & 1u)) >> 16);
}

// bucket of row r: floor(r*1536/50000) = floor(r*96/3125); exact for r < 50000
__device__ __forceinline__ int bucket_of(unsigned r) {
    return (int)((r * 96u) / 3125u);
}

// ---------------------------------------------------------------------------
// K_FRONT: fused {W-swizzle + GEMM} | {edge binning}. The two halves are
// data-independent; branching on blockIdx overlaps the MFMA-bound gemm with
// the BW-bound binning and removes two kernel-launch gaps.
//   blocks [0, GBLK):          h = X @ W^T, 128 rows/block (8 waves x 16 rows)
//   blocks [GBLK, GBLK+NBLK):  bin CH=4800 edges into 1536 row-buckets
// ---------------------------------------------------------------------------
__global__ __launch_bounds__(512) void k_front(const float* __restrict__ X,
                                               const float* __restrict__ W,
                                               const int* __restrict__ rows,
                                               const int* __restrict__ cols,
                                               const float* __restrict__ vals,
                                               const float* __restrict__ alpha,
                                               unsigned short* __restrict__ hb16,
                                               uint2* __restrict__ out1,
                                               unsigned short* __restrict__ off1) {
    // union LDS: gemm needs 32KB (Wl), bin needs 54,144B (stg+rnk+sA)
    __shared__ __align__(16) char smem[54144];
    const int t = threadIdx.x;

    if (blockIdx.x < GBLK) {
        // ---------------- GEMM path ----------------
        uint4* Wl = (uint4*)smem;   // 2048 records = 32KB
        // stage W with MFMA B-fragment swizzle (per-block; W is L2-resident)
        for (int i = t; i < 2048; i += 512) {
            const int nt   = i >> 8;         // 0..7
            const int kc   = (i >> 6) & 3;   // 0..3
            const int lane = i & 63;
            const int n  = nt * 16 + (lane & 15);
            const int k0 = kc * 32 + (lane >> 4) * 8;
            const float* src = W + (size_t)n * 128 + k0;
            float4 a = *(const float4*)(src);
            float4 b = *(const float4*)(src + 4);
            unsigned u0 = (unsigned)f2bf(a.x) | ((unsigned)f2bf(a.y) << 16);
            unsigned u1 = (unsigned)f2bf(a.z) | ((unsigned)f2bf(a.w) << 16);
            unsigned u2 = (unsigned)f2bf(b.x) | ((unsigned)f2bf(b.y) << 16);
            unsigned u3 = (unsigned)f2bf(b.z) | ((unsigned)f2bf(b.w) << 16);
            Wl[i] = make_uint4(u0, u1, u2, u3);
        }
        __syncthreads();

        const int w    = t >> 6;
        const int lane = t & 63;
        const int q    = lane >> 4;
        const int ml   = lane & 15;
        const int m0   = blockIdx.x * 128 + w * 16;

        int xr = m0 + ml; if (xr >= NNODES) xr = NNODES - 1;   // clamp (stores guarded)
        const float* xrow = X + (size_t)xr * 128;

        bf16x8 xf[4];
#pragma unroll
        for (int kc = 0; kc < 4; ++kc) {
            const int k0 = kc * 32 + q * 8;
            float4 a = *(const float4*)(xrow + k0);
            float4 b = *(const float4*)(xrow + k0 + 4);
            bf16x8 v;
            v[0] = (short)f2bf(a.x); v[1] = (short)f2bf(a.y);
            v[2] = (short)f2bf(a.z); v[3] = (short)f2bf(a.w);
            v[4] = (short)f2bf(b.x); v[5] = (short)f2bf(b.y);
            v[6] = (short)f2bf(b.z); v[7] = (short)f2bf(b.w);
            xf[kc] = v;
        }

#pragma unroll
        for (int nt = 0; nt < 8; ++nt) {
            f32x4 acc = {0.f, 0.f, 0.f, 0.f};
#pragma unroll
            for (int kc = 0; kc < 4; ++kc) {
                const bf16x8 wf = *(const bf16x8*)&Wl[(nt * 4 + kc) * 64 + lane];
                acc = __builtin_amdgcn_mfma_f32_16x16x32_bf16(xf[kc], wf, acc, 0, 0, 0);
            }
#pragma unroll
            for (int r = 0; r < 4; ++r) {
                const int row = m0 + q * 4 + r;
                if (row < NNODES)
                    hb16[(size_t)row * 128 + nt * 16 + ml] = f2bf(acc[r]);
            }
        }
    } else {
        // ---------------- BIN path ----------------
        uint2*          stg = (uint2*)smem;                      // 38,400 B
        unsigned short* rnk = (unsigned short*)(smem + 38400);   //  9,600 B
        int*            sA  = (int*)(smem + 48000);              //  6,144 B
        const int bb    = blockIdx.x - GBLK;
        const int start = bb * CH;                               // end = start+CH (exact fit)

        const float g0 = 1.0f / (1.0f + __expf(-alpha[0]));
        const float g1 = 1.0f / (1.0f + __expf(-alpha[1]));
        const float g2 = 1.0f / (1.0f + __expf(-alpha[2]));

#pragma unroll
        for (int j = 0; j < 3; ++j) sA[t + j * 512] = 0;
        __syncthreads();

        // pass 1: read globals once, pack record into LDS, histogram + rank
        for (int k = t; k < CH; k += 512) {
            const int idx = start + k;
            const int r = rows[idx];
            const int c = cols[idx];
            const float v = vals[idx];
            const float gv = v * (idx < NEDGE ? g0 : (idx < 2 * NEDGE ? g1 : g2));
            uint2 rec;
            rec.x = ((unsigned)r << 16) | (unsigned)c;   // both < 65536
            rec.y = __float_as_uint(gv);
            stg[k] = rec;
            rnk[k] = (unsigned short)atomicAdd(&sA[bucket_of((unsigned)r)], 1);
        }
        __syncthreads();

        // in-place inclusive scan over 1536 (11 steps, two barriers per step)
        for (int off = 1; off < 1536; off <<= 1) {
            int v[3];
#pragma unroll
            for (int j = 0; j < 3; ++j) {
                const int i = t + j * 512;
                v[j] = sA[i] + ((i >= off) ? sA[i - off] : 0);
            }
            __syncthreads();
#pragma unroll
            for (int j = 0; j < 3; ++j) sA[t + j * 512] = v[j];
            __syncthreads();
        }

        // off1 = exclusive offsets (values <= 4800 -> u16)
        for (int b = t; b < NBUK; b += 512)
            off1[(size_t)bb * OS + b] = (unsigned short)(b ? sA[b - 1] : 0);
        if (t == 0) off1[(size_t)bb * OS + NBUK] = (unsigned short)sA[NBUK - 1];

        // pass 2: position = base[bucket] + rank, grouped write, no atomics
        for (int k = t; k < CH; k += 512) {
            const uint2 rec = stg[k];
            const int b = bucket_of(rec.x >> 16);
            const int pos = (b ? sA[b - 1] : 0) + (int)rnk[k];
            out1[(size_t)bb * CH + pos] = rec;
        }
    }
}

// ---------------------------------------------------------------------------
// K_AGG: one block (512 thr = 8 waves) per 32/33-row bucket. 1536 blocks at
// 4/CU wave-capped occupancy -> 6 pipelined blocks/CU (no makespan tail).
// SINGLE global read of out1 (r1's double-read cost +95MB HBM = +15us):
// records staged in LDS, then scattered LDS->LDS directly into row-sorted
// colS/valS (order within a row irrelevant for a sum) -> gather loop has zero
// indirection: one aligned ds_read_b128 yields 8 cols, then 8 independent
// coalesced 256B global gathers. Row bases 8-padded for 16B-aligned reads.
// ---------------------------------------------------------------------------
__global__ __launch_bounds__(512) void k_agg(const unsigned* __restrict__ hbits,
                                             const uint2* __restrict__ out1,
                                             const unsigned short* __restrict__ off1,
                                             float* __restrict__ out) {
    __shared__ __align__(16) uint2          stg[STGCAP];   // 15,360 B
    __shared__ __align__(16) unsigned short colS[SCAP];    //  4,352 B
    __shared__ __align__(16) float          valS[SCAP];    //  8,704 B
    __shared__ int rh[40], rbase[40], rcur[40];
    __shared__ int sA[512];
    const int t = threadIdx.x;
    const int b = blockIdx.x;

    // bucket row range: [ceil(b*3125/96), ceil((b+1)*3125/96))
    const int sstart = (b * 3125 + 95) / 96;
    const int send   = ((b + 1) * 3125 + 95) / 96;
    const int width  = send - sstart;                      // 32 or 33

    if (t < 40) rh[t] = 0;

    // one segment per thread (NBLK=500 <= 512)
    int s0 = 0, e0 = 0;
    if (t < NBLK) {
        s0 = off1[(size_t)t * OS + b];
        e0 = off1[(size_t)t * OS + b + 1];
    }
    const int len = e0 - s0;
    sA[t] = len;
    __syncthreads();

    // 512-wide inclusive scan -> per-thread staging base
    for (int off = 1; off < 512; off <<= 1) {
        const int v = sA[t] + ((t >= off) ? sA[t - off] : 0);
        __syncthreads();
        sA[t] = v;
        __syncthreads();
    }
    const int base = sA[t] - len;

    // P1: single global read; stage + per-row histogram
    {
        const uint2* seg = out1 + (size_t)t * CH;
        int p = base;
        for (int i = s0; i < e0; ++i, ++p) {
            const uint2 rec = seg[i];
            if (p < STGCAP) {
                stg[p] = rec;
                atomicAdd(&rh[(int)(rec.x >> 16) - sstart], 1);
            }
        }
    }
    __syncthreads();

    // P2: scan of 8-padded counts -> 8-aligned row bases (sA reuse is safe)
    if (t < 64) sA[t] = (t < width) ? ((rh[t] + 7) & ~7) : 0;
    __syncthreads();
    for (int off = 1; off < 64; off <<= 1) {
        int v = 0;
        if (t < 64) v = sA[t] + ((t >= off) ? sA[t - off] : 0);
        __syncthreads();
        if (t < 64) sA[t] = v;
        __syncthreads();
    }
    if (t < width) {
        const int rb = sA[t] - ((rh[t] + 7) & ~7);
        rbase[t] = rb;
        rcur[t]  = rb;
    }
    __syncthreads();

    // P3: LDS->LDS scatter straight into sorted position (pos < SCAP by cap math)
    {
        const int lim = (base + len < STGCAP) ? (base + len) : STGCAP;
        for (int k = base; k < lim; ++k) {
            const uint2 rec = stg[k];
            const int lr  = (int)(rec.x >> 16) - sstart;
            const int pos = atomicAdd(&rcur[lr], 1);
            colS[pos] = (unsigned short)(rec.x & 0xffffu);
            valS[pos] = __uint_as_float(rec.y);
        }
    }
    __syncthreads();

    // P4: gather. Wave w owns rows lr = w, w+8, ... (4-5 rows each).
    const int w    = t >> 6;
    const int lane = t & 63;
    for (int lr = w; lr < width; lr += 8) {
        const int s   = rbase[lr];
        const int cnt = rh[lr];
        float2 acc = make_float2(0.f, 0.f);
        int i = 0;
        for (; i + 8 <= cnt; i += 8) {
            const uint4  cv = *(const uint4*)&colS[s + i];     // 8 cols, 16B-aligned
            const float4 va = *(const float4*)&valS[s + i];
            const float4 vb = *(const float4*)&valS[s + i + 4];
            unsigned hb[8];
            hb[0] = hbits[(size_t)(cv.x & 0xffffu) * 64 + lane];
            hb[1] = hbits[(size_t)(cv.x >> 16)     * 64 + lane];
            hb[2] = hbits[(size_t)(cv.y & 0xffffu) * 64 + lane];
            hb[3] = hbits[(size_t)(cv.y >> 16)     * 64 + lane];
            hb[4] = hbits[(size_t)(cv.z & 0xffffu) * 64 + lane];
            hb[5] = hbits[(size_t)(cv.z >> 16)     * 64 + lane];
            hb[6] = hbits[(size_t)(cv.w & 0xffffu) * 64 + lane];
            hb[7] = hbits[(size_t)(cv.w >> 16)     * 64 + lane];
            const float vv[8] = {va.x, va.y, va.z, va.w, vb.x, vb.y, vb.z, vb.w};
#pragma unroll
            for (int j = 0; j < 8; ++j) {
                acc.x += vv[j] * __uint_as_float(hb[j] << 16);
                acc.y += vv[j] * __uint_as_float(hb[j] & 0xffff0000u);
            }
        }
        for (; i < cnt; ++i) {
            const unsigned c   = colS[s + i];
            const float    v   = valS[s + i];
            const unsigned hbv = hbits[(size_t)c * 64 + lane];
            acc.x += v * __uint_as_float(hbv << 16);
            acc.y += v * __uint_as_float(hbv & 0xffff0000u);
        }
        const int row = sstart + lr;
        ((float2*)out)[(size_t)row * 64 + lane] = acc;
    }
}

extern "C" void kernel_launch(void* const* d_in, const int* in_sizes, int n_in,
                              void* d_out, int out_size, void* d_ws, size_t ws_size,
                              hipStream_t stream) {
    const float* X     = (const float*)d_in[0];
    const float* W     = (const float*)d_in[1];
    const float* alpha = (const float*)d_in[2];
    const int*   rows  = (const int*)d_in[3];
    const int*   cols  = (const int*)d_in[4];
    const float* vals  = (const float*)d_in[5];
    float* out = (float*)d_out;

    // workspace layout (stays under the proven 33.87MB footprint)
    char* ws = (char*)d_ws;
    unsigned*       hbits = (unsigned*)(ws + 0);            // 12,800,000 B
    unsigned short* hb16  = (unsigned short*)(ws + 0);      // same bytes, u16 view
    uint2*          out1  = (uint2*)(ws + 12800000);        // 19,200,000 B
    unsigned short* off1  = (unsigned short*)(ws + 32000000); // 500*1537*2 = 1,537,000 B
    // total: 33,537,000 B

    hipLaunchKernelGGL(k_front, dim3(FGRID), dim3(512), 0, stream,
                       X, W, rows, cols, vals, alpha, hb16, out1, off1);
    hipLaunchKernelGGL(k_agg, dim3(NBUK), dim3(512), 0, stream,
                       hbits, out1, off1, out);
}

// Round 3
// 219.252 us; speedup vs baseline: 1.1733x; 1.0075x over previous
//
#include <hip/hip_runtime.h>
#include <math.h>

#define NNODES 50000
#define NEDGE  800000
#define NG     3
#define GE     (NG*NEDGE)            // 2,400,000 combined edges
#define NBUK   1536                  // row buckets: bucket(r) = r*96/3125 -> 32/33 rows each
#define OS     (NBUK + 1)            // 1537, off1 row stride
#define CH     4688                  // edges per bin block -> exactly 512 bin blocks
#define NBLK   512                   // == k_agg block size: 1 segment per thread
#define GBLK   391                   // gemm sub-grid blocks of 128 rows (391*128 = 50048)
#define FGRID  (GBLK + NBLK)         // 903 fused front-kernel blocks
#define STGCAP 1920                  // raw record cap per bucket (mean 1562, sigma 40; 9-sigma margin)
#define SCAP   2176                  // sorted cap: STGCAP + 33*7 = 2151 worst -> never overflows

typedef __attribute__((ext_vector_type(8))) short bf16x8;
typedef __attribute__((ext_vector_type(4))) float f32x4;

// fp32 -> bf16 round-to-nearest-even (no NaN inputs here)
__device__ __forceinline__ unsigned short f2bf(float f) {
    unsigned u = __float_as_uint(f);
    return (unsigned short)((u + 0x7fffu + ((u >> 16) & 1u)) >> 16);
}

// bucket of row r: floor(r*1536/50000) = floor(r*96/3125); exact for r < 50000
__device__ __forceinline__ int bucket_of(unsigned r) {
    return (int)((r * 96u) / 3125u);
}

// ---------------------------------------------------------------------------
// K_FRONT: fused {W-swizzle + GEMM} | {edge binning}.
//   blocks [0, GBLK):          h = X @ W^T, 128 rows/block (8 waves x 16 rows)
//   blocks [GBLK, GBLK+NBLK):  bin CH=4688 edges into 1536 row-buckets
// GEMM epilogue rewritten: accumulators held in regs across all 8 col-tiles,
// then a per-wave LDS transpose (reusing the Wl region) and fully-coalesced
// dwordx4 stores -- replaces 6.4M scattered 2B global stores (suspected cause
// of the inferred ~112us front time).
// ---------------------------------------------------------------------------
__global__ __launch_bounds__(512) void k_front(const float* __restrict__ X,
                                               const float* __restrict__ W,
                                               const int* __restrict__ rows,
                                               const int* __restrict__ cols,
                                               const float* __restrict__ vals,
                                               const float* __restrict__ alpha,
                                               unsigned short* __restrict__ hb16,
                                               uint2* __restrict__ out1,
                                               unsigned short* __restrict__ off1) {
    // union LDS: gemm needs 32KB (Wl) then 34.8KB (transpose); bin needs 53,024B
    __shared__ __align__(16) char smem[53024];
    const int t = threadIdx.x;

    if (blockIdx.x < GBLK) {
        // ---------------- GEMM path ----------------
        uint4* Wl = (uint4*)smem;   // 2048 records = 32KB
        for (int i = t; i < 2048; i += 512) {
            const int nt   = i >> 8;         // 0..7
            const int kc   = (i >> 6) & 3;   // 0..3
            const int lane = i & 63;
            const int n  = nt * 16 + (lane & 15);
            const int k0 = kc * 32 + (lane >> 4) * 8;
            const float* src = W + (size_t)n * 128 + k0;
            float4 a = *(const float4*)(src);
            float4 b = *(const float4*)(src + 4);
            unsigned u0 = (unsigned)f2bf(a.x) | ((unsigned)f2bf(a.y) << 16);
            unsigned u1 = (unsigned)f2bf(a.z) | ((unsigned)f2bf(a.w) << 16);
            unsigned u2 = (unsigned)f2bf(b.x) | ((unsigned)f2bf(b.y) << 16);
            unsigned u3 = (unsigned)f2bf(b.z) | ((unsigned)f2bf(b.w) << 16);
            Wl[i] = make_uint4(u0, u1, u2, u3);
        }
        __syncthreads();

        const int w    = t >> 6;
        const int lane = t & 63;
        const int q    = lane >> 4;
        const int ml   = lane & 15;
        const int m0   = blockIdx.x * 128 + w * 16;

        int xr = m0 + ml; if (xr >= NNODES) xr = NNODES - 1;   // clamp (stores guarded)
        const float* xrow = X + (size_t)xr * 128;

        bf16x8 xf[4];
#pragma unroll
        for (int kc = 0; kc < 4; ++kc) {
            const int k0 = kc * 32 + q * 8;
            float4 a = *(const float4*)(xrow + k0);
            float4 b = *(const float4*)(xrow + k0 + 4);
            bf16x8 v;
            v[0] = (short)f2bf(a.x); v[1] = (short)f2bf(a.y);
            v[2] = (short)f2bf(a.z); v[3] = (short)f2bf(a.w);
            v[4] = (short)f2bf(b.x); v[5] = (short)f2bf(b.y);
            v[6] = (short)f2bf(b.z); v[7] = (short)f2bf(b.w);
            xf[kc] = v;
        }

        f32x4 acc[8];
#pragma unroll
        for (int nt = 0; nt < 8; ++nt) acc[nt] = (f32x4){0.f, 0.f, 0.f, 0.f};
#pragma unroll
        for (int nt = 0; nt < 8; ++nt)
#pragma unroll
            for (int kc = 0; kc < 4; ++kc) {
                const bf16x8 wf = *(const bf16x8*)&Wl[(nt * 4 + kc) * 64 + lane];
                acc[nt] = __builtin_amdgcn_mfma_f32_16x16x32_bf16(xf[kc], wf, acc[nt], 0, 0, 0);
            }
        __syncthreads();   // all waves done reading Wl; reuse region for transpose

        // per-wave 16x128 u16 tile, row stride 136 u16 (272B: 16B-aligned, banks spread)
        unsigned short* hst = (unsigned short*)smem + w * 2176;
#pragma unroll
        for (int nt = 0; nt < 8; ++nt)
#pragma unroll
            for (int r = 0; r < 4; ++r)
                hst[(q * 4 + r) * 136 + nt * 16 + ml] = f2bf(acc[nt][r]);
        __syncthreads();

        // coalesced store: 16-lane groups write full 256B rows
#pragma unroll
        for (int i = 0; i < 4; ++i) {
            const int chunk = i * 64 + lane;        // 0..255
            const int lr    = chunk >> 4;           // 0..15
            const int cc    = chunk & 15;           // 0..15 (16B units)
            const int row   = m0 + lr;
            const uint4 v = *(const uint4*)(hst + lr * 136 + cc * 8);
            if (row < NNODES)
                ((uint4*)(hb16 + (size_t)row * 128))[cc] = v;
        }
    } else {
        // ---------------- BIN path ----------------
        uint2*          stg = (uint2*)smem;                      // 37,504 B
        unsigned short* rnk = (unsigned short*)(smem + 37504);   //  9,376 B
        int*            sA  = (int*)(smem + 46880);              //  6,144 B
        const int bb    = blockIdx.x - GBLK;
        const int start = bb * CH;
        const int end   = (start + CH < GE) ? (start + CH) : GE;
        const int len   = end - start;

        const float g0 = 1.0f / (1.0f + __expf(-alpha[0]));
        const float g1 = 1.0f / (1.0f + __expf(-alpha[1]));
        const float g2 = 1.0f / (1.0f + __expf(-alpha[2]));

#pragma unroll
        for (int j = 0; j < 3; ++j) sA[t + j * 512] = 0;
        __syncthreads();

        // pass 1: read globals once, pack record into LDS, histogram + rank
        for (int k = t; k < len; k += 512) {
            const int idx = start + k;
            const int r = rows[idx];
            const int c = cols[idx];
            const float v = vals[idx];
            const float gv = v * (idx < NEDGE ? g0 : (idx < 2 * NEDGE ? g1 : g2));
            uint2 rec;
            rec.x = ((unsigned)r << 16) | (unsigned)c;   // both < 65536
            rec.y = __float_as_uint(gv);
            stg[k] = rec;
            rnk[k] = (unsigned short)atomicAdd(&sA[bucket_of((unsigned)r)], 1);
        }
        __syncthreads();

        // in-place inclusive scan over 1536 (11 steps)
        for (int off = 1; off < 1536; off <<= 1) {
            int v[3];
#pragma unroll
            for (int j = 0; j < 3; ++j) {
                const int i = t + j * 512;
                v[j] = sA[i] + ((i >= off) ? sA[i - off] : 0);
            }
            __syncthreads();
#pragma unroll
            for (int j = 0; j < 3; ++j) sA[t + j * 512] = v[j];
            __syncthreads();
        }

        // off1 = exclusive offsets (values <= 4688 -> u16)
        if (t < NBUK) off1[(size_t)bb * OS + t] = (unsigned short)(t ? sA[t - 1] : 0);
        for (int b = t + 512; b < NBUK; b += 512)
            off1[(size_t)bb * OS + b] = (unsigned short)sA[b - 1];
        if (t == 0) off1[(size_t)bb * OS + NBUK] = (unsigned short)sA[NBUK - 1];

        // pass 2: position = base[bucket] + rank, grouped write, no atomics
        for (int k = t; k < len; k += 512) {
            const uint2 rec = stg[k];
            const int b = bucket_of(rec.x >> 16);
            const int pos = (b ? sA[b - 1] : 0) + (int)rnk[k];
            out1[(size_t)bb * CH + pos] = rec;
        }
    }
}

// ---------------------------------------------------------------------------
// K_AGG: one block (512 thr = 8 waves) per 32/33-row bucket, NBLK=512 segments
// (exactly one per thread). Latency attack: gather loop unrolled 16-wide
// (16 outstanding loads/thread) and row regions zero-padded to multiples of 8
// (pad col=0, val=0 contributes nothing) -> no scalar tail at all.
// ---------------------------------------------------------------------------
__global__ __launch_bounds__(512, 8) void k_agg(const unsigned* __restrict__ hbits,
                                                const uint2* __restrict__ out1,
                                                const unsigned short* __restrict__ off1,
                                                float* __restrict__ out) {
    __shared__ __align__(16) uint2          stg[STGCAP];   // 15,360 B
    __shared__ __align__(16) unsigned short colS[SCAP];    //  4,352 B
    __shared__ __align__(16) float          valS[SCAP];    //  8,704 B
    __shared__ int rh[40], rbase[40], rcur[40];
    __shared__ int sA[512];
    const int t = threadIdx.x;
    const int b = blockIdx.x;

    // bucket row range: [ceil(b*3125/96), ceil((b+1)*3125/96))
    const int sstart = (b * 3125 + 95) / 96;
    const int send   = ((b + 1) * 3125 + 95) / 96;
    const int width  = send - sstart;                      // 32 or 33

    if (t < 40) rh[t] = 0;

    // exactly one segment per thread
    const int s0 = off1[(size_t)t * OS + b];
    const int e0 = off1[(size_t)t * OS + b + 1];
    const int len = e0 - s0;
    sA[t] = len;
    __syncthreads();

    // 512-wide inclusive scan -> per-thread staging base
    for (int off = 1; off < 512; off <<= 1) {
        const int v = sA[t] + ((t >= off) ? sA[t - off] : 0);
        __syncthreads();
        sA[t] = v;
        __syncthreads();
    }
    const int base = sA[t] - len;

    // P1: single global read; stage + per-row histogram
    {
        const uint2* seg = out1 + (size_t)t * CH;
        int p = base;
        for (int i = s0; i < e0; ++i, ++p) {
            const uint2 rec = seg[i];
            if (p < STGCAP) {
                stg[p] = rec;
                atomicAdd(&rh[(int)(rec.x >> 16) - sstart], 1);
            }
        }
    }
    __syncthreads();

    // P2: scan of 8-padded counts -> 8-aligned row bases
    if (t < 64) sA[t] = (t < width) ? ((rh[t] + 7) & ~7) : 0;
    __syncthreads();
    for (int off = 1; off < 64; off <<= 1) {
        int v = 0;
        if (t < 64) v = sA[t] + ((t >= off) ? sA[t - off] : 0);
        __syncthreads();
        if (t < 64) sA[t] = v;
        __syncthreads();
    }
    if (t < width) {
        const int c  = rh[t];
        const int c8 = (c + 7) & ~7;
        const int rb = sA[t] - c8;
        rbase[t] = rb;
        rcur[t]  = rb;
        // zero-fill pad slots [rb+c, rb+c8): col 0 / val 0 -> no contribution
        for (int k = rb + c; k < rb + c8; ++k) { colS[k] = 0; valS[k] = 0.f; }
    }
    __syncthreads();

    // P3: LDS->LDS scatter straight into sorted position
    {
        const int lim = (base + len < STGCAP) ? (base + len) : STGCAP;
        for (int k = base; k < lim; ++k) {
            const uint2 rec = stg[k];
            const int lr  = (int)(rec.x >> 16) - sstart;
            const int pos = atomicAdd(&rcur[lr], 1);
            colS[pos] = (unsigned short)(rec.x & 0xffffu);
            valS[pos] = __uint_as_float(rec.y);
        }
    }
    __syncthreads();

    // P4: gather, 16 outstanding loads per thread, no tails.
    const int w    = t >> 6;
    const int lane = t & 63;
    for (int lr = w; lr < width; lr += 8) {
        const int s    = rbase[lr];
        const int cnt8 = (rh[lr] + 7) & ~7;
        float2 acc = make_float2(0.f, 0.f);
        int i = 0;
        for (; i + 16 <= cnt8; i += 16) {
            const uint4  c0 = *(const uint4*)&colS[s + i];
            const uint4  c1 = *(const uint4*)&colS[s + i + 8];
            const float4 v0 = *(const float4*)&valS[s + i];
            const float4 v1 = *(const float4*)&valS[s + i + 4];
            const float4 v2 = *(const float4*)&valS[s + i + 8];
            const float4 v3 = *(const float4*)&valS[s + i + 12];
            unsigned hb[16];
            hb[0]  = hbits[(size_t)(c0.x & 0xffffu) * 64 + lane];
            hb[1]  = hbits[(size_t)(c0.x >> 16)     * 64 + lane];
            hb[2]  = hbits[(size_t)(c0.y & 0xffffu) * 64 + lane];
            hb[3]  = hbits[(size_t)(c0.y >> 16)     * 64 + lane];
            hb[4]  = hbits[(size_t)(c0.z & 0xffffu) * 64 + lane];
            hb[5]  = hbits[(size_t)(c0.z >> 16)     * 64 + lane];
            hb[6]  = hbits[(size_t)(c0.w & 0xffffu) * 64 + lane];
            hb[7]  = hbits[(size_t)(c0.w >> 16)     * 64 + lane];
            hb[8]  = hbits[(size_t)(c1.x & 0xffffu) * 64 + lane];
            hb[9]  = hbits[(size_t)(c1.x >> 16)     * 64 + lane];
            hb[10] = hbits[(size_t)(c1.y & 0xffffu) * 64 + lane];
            hb[11] = hbits[(size_t)(c1.y >> 16)     * 64 + lane];
            hb[12] = hbits[(size_t)(c1.z & 0xffffu) * 64 + lane];
            hb[13] = hbits[(size_t)(c1.z >> 16)     * 64 + lane];
            hb[14] = hbits[(size_t)(c1.w & 0xffffu) * 64 + lane];
            hb[15] = hbits[(size_t)(c1.w >> 16)     * 64 + lane];
            const float vv[16] = {v0.x, v0.y, v0.z, v0.w, v1.x, v1.y, v1.z, v1.w,
                                  v2.x, v2.y, v2.z, v2.w, v3.x, v3.y, v3.z, v3.w};
#pragma unroll
            for (int j = 0; j < 16; ++j) {
                acc.x += vv[j] * __uint_as_float(hb[j] << 16);
                acc.y += vv[j] * __uint_as_float(hb[j] & 0xffff0000u);
            }
        }
        if (i < cnt8) {   // exactly one 8-block remains (cnt8 is a multiple of 8)
            const uint4  c0 = *(const uint4*)&colS[s + i];
            const float4 v0 = *(const float4*)&valS[s + i];
            const float4 v1 = *(const float4*)&valS[s + i + 4];
            unsigned hb[8];
            hb[0] = hbits[(size_t)(c0.x & 0xffffu) * 64 + lane];
            hb[1] = hbits[(size_t)(c0.x >> 16)     * 64 + lane];
            hb[2] = hbits[(size_t)(c0.y & 0xffffu) * 64 + lane];
            hb[3] = hbits[(size_t)(c0.y >> 16)     * 64 + lane];
            hb[4] = hbits[(size_t)(c0.z & 0xffffu) * 64 + lane];
            hb[5] = hbits[(size_t)(c0.z >> 16)     * 64 + lane];
            hb[6] = hbits[(size_t)(c0.w & 0xffffu) * 64 + lane];
            hb[7] = hbits[(size_t)(c0.w >> 16)     * 64 + lane];
            const float vv[8] = {v0.x, v0.y, v0.z, v0.w, v1.x, v1.y, v1.z, v1.w};
#pragma unroll
            for (int j = 0; j < 8; ++j) {
                acc.x += vv[j] * __uint_as_float(hb[j] << 16);
                acc.y += vv[j] * __uint_as_float(hb[j] & 0xffff0000u);
            }
        }
        const int row = sstart + lr;
        ((float2*)out)[(size_t)row * 64 + lane] = acc;
    }
}

extern "C" void kernel_launch(void* const* d_in, const int* in_sizes, int n_in,
                              void* d_out, int out_size, void* d_ws, size_t ws_size,
                              hipStream_t stream) {
    const float* X     = (const float*)d_in[0];
    const float* W     = (const float*)d_in[1];
    const float* alpha = (const float*)d_in[2];
    const int*   rows  = (const int*)d_in[3];
    const int*   cols  = (const int*)d_in[4];
    const float* vals  = (const float*)d_in[5];
    float* out = (float*)d_out;

    // workspace layout (<= 33,870,176 B proven footprint)
    char* ws = (char*)d_ws;
    unsigned*       hbits = (unsigned*)(ws + 0);              // 12,800,000 B
    unsigned short* hb16  = (unsigned short*)(ws + 0);        // same bytes, u16 view
    uint2*          out1  = (uint2*)(ws + 12800000);          // 512*4688*8 = 19,202,048 B
    unsigned short* off1  = (unsigned short*)(ws + 32002048); // 512*1537*2 =  1,573,888 B
    // total: 33,575,936 B

    hipLaunchKernelGGL(k_front, dim3(FGRID), dim3(512), 0, stream,
                       X, W, rows, cols, vals, alpha, hb16, out1, off1);
    hipLaunchKernelGGL(k_agg, dim3(NBUK), dim3(512), 0, stream,
                       hbits, out1, off1, out);
}

// Round 4
// 212.811 us; speedup vs baseline: 1.2088x; 1.0303x over previous
//
#include <hip/hip_runtime.h>
#include <math.h>

#define NNODES 50000
#define NEDGE  800000
#define NG     3
#define GE     (NG*NEDGE)            // 2,400,000 combined edges
#define NBUK   1536                  // row buckets: bucket(r) = r*96/3125 -> 32/33 rows each
#define OS     (NBUK + 1)            // 1537, off1 row stride
#define CH     4688                  // edges per bin block -> exactly 512 bin blocks
#define NBLK   512                   // == k_agg block size: 1 segment per thread
#define GBLK   391                   // gemm sub-grid blocks of 128 rows (391*128 = 50048)
#define FGRID  (GBLK + NBLK)         // 903 fused front-kernel blocks
#define STGCAP 1920                  // raw record cap per bucket (mean 1562, sigma 40; 9-sigma margin)
#define NPH    7                     // col phases: col>>13 -> 8192-col windows (2MB of hbits each)
#define MAXG   231                   // max groups = NPH * 33
#define SCAP   2624                  // sorted cap: STGCAP + MAXG*3 = 2613 -> never overflows

typedef __attribute__((ext_vector_type(8))) short bf16x8;
typedef __attribute__((ext_vector_type(4))) float f32x4;

// fp32 -> bf16 round-to-nearest-even (no NaN inputs here)
__device__ __forceinline__ unsigned short f2bf(float f) {
    unsigned u = __float_as_uint(f);
    return (unsigned short)((u + 0x7fffu + ((u >> 16) & 1u)) >> 16);
}

// bucket of row r: floor(r*1536/50000) = floor(r*96/3125); exact for r < 50000
__device__ __forceinline__ int bucket_of(unsigned r) {
    return (int)((r * 96u) / 3125u);
}

// ---------------------------------------------------------------------------
// K_FRONT: fused {W-swizzle + GEMM} | {edge binning}. UNCHANGED from r3 (it
// never surfaced in top-5 -> dur in [95,103]us; once k_agg drops below it,
// its counters become visible for the next round's attack).
// ---------------------------------------------------------------------------
__global__ __launch_bounds__(512) void k_front(const float* __restrict__ X,
                                               const float* __restrict__ W,
                                               const int* __restrict__ rows,
                                               const int* __restrict__ cols,
                                               const float* __restrict__ vals,
                                               const float* __restrict__ alpha,
                                               unsigned short* __restrict__ hb16,
                                               uint2* __restrict__ out1,
                                               unsigned short* __restrict__ off1) {
    __shared__ __align__(16) char smem[53024];
    const int t = threadIdx.x;

    if (blockIdx.x < GBLK) {
        // ---------------- GEMM path ----------------
        uint4* Wl = (uint4*)smem;   // 2048 records = 32KB
        for (int i = t; i < 2048; i += 512) {
            const int nt   = i >> 8;
            const int kc   = (i >> 6) & 3;
            const int lane = i & 63;
            const int n  = nt * 16 + (lane & 15);
            const int k0 = kc * 32 + (lane >> 4) * 8;
            const float* src = W + (size_t)n * 128 + k0;
            float4 a = *(const float4*)(src);
            float4 b = *(const float4*)(src + 4);
            unsigned u0 = (unsigned)f2bf(a.x) | ((unsigned)f2bf(a.y) << 16);
            unsigned u1 = (unsigned)f2bf(a.z) | ((unsigned)f2bf(a.w) << 16);
            unsigned u2 = (unsigned)f2bf(b.x) | ((unsigned)f2bf(b.y) << 16);
            unsigned u3 = (unsigned)f2bf(b.z) | ((unsigned)f2bf(b.w) << 16);
            Wl[i] = make_uint4(u0, u1, u2, u3);
        }
        __syncthreads();

        const int w    = t >> 6;
        const int lane = t & 63;
        const int q    = lane >> 4;
        const int ml   = lane & 15;
        const int m0   = blockIdx.x * 128 + w * 16;

        int xr = m0 + ml; if (xr >= NNODES) xr = NNODES - 1;
        const float* xrow = X + (size_t)xr * 128;

        bf16x8 xf[4];
#pragma unroll
        for (int kc = 0; kc < 4; ++kc) {
            const int k0 = kc * 32 + q * 8;
            float4 a = *(const float4*)(xrow + k0);
            float4 b = *(const float4*)(xrow + k0 + 4);
            bf16x8 v;
            v[0] = (short)f2bf(a.x); v[1] = (short)f2bf(a.y);
            v[2] = (short)f2bf(a.z); v[3] = (short)f2bf(a.w);
            v[4] = (short)f2bf(b.x); v[5] = (short)f2bf(b.y);
            v[6] = (short)f2bf(b.z); v[7] = (short)f2bf(b.w);
            xf[kc] = v;
        }

        f32x4 acc[8];
#pragma unroll
        for (int nt = 0; nt < 8; ++nt) acc[nt] = (f32x4){0.f, 0.f, 0.f, 0.f};
#pragma unroll
        for (int nt = 0; nt < 8; ++nt)
#pragma unroll
            for (int kc = 0; kc < 4; ++kc) {
                const bf16x8 wf = *(const bf16x8*)&Wl[(nt * 4 + kc) * 64 + lane];
                acc[nt] = __builtin_amdgcn_mfma_f32_16x16x32_bf16(xf[kc], wf, acc[nt], 0, 0, 0);
            }
        __syncthreads();

        unsigned short* hst = (unsigned short*)smem + w * 2176;
#pragma unroll
        for (int nt = 0; nt < 8; ++nt)
#pragma unroll
            for (int r = 0; r < 4; ++r)
                hst[(q * 4 + r) * 136 + nt * 16 + ml] = f2bf(acc[nt][r]);
        __syncthreads();

#pragma unroll
        for (int i = 0; i < 4; ++i) {
            const int chunk = i * 64 + lane;
            const int lr    = chunk >> 4;
            const int cc    = chunk & 15;
            const int row   = m0 + lr;
            const uint4 v = *(const uint4*)(hst + lr * 136 + cc * 8);
            if (row < NNODES)
                ((uint4*)(hb16 + (size_t)row * 128))[cc] = v;
        }
    } else {
        // ---------------- BIN path ----------------
        uint2*          stg = (uint2*)smem;                      // 37,504 B
        unsigned short* rnk = (unsigned short*)(smem + 37504);   //  9,376 B
        int*            sA  = (int*)(smem + 46880);              //  6,144 B
        const int bb    = blockIdx.x - GBLK;
        const int start = bb * CH;
        const int end   = (start + CH < GE) ? (start + CH) : GE;
        const int len   = end - start;

        const float g0 = 1.0f / (1.0f + __expf(-alpha[0]));
        const float g1 = 1.0f / (1.0f + __expf(-alpha[1]));
        const float g2 = 1.0f / (1.0f + __expf(-alpha[2]));

#pragma unroll
        for (int j = 0; j < 3; ++j) sA[t + j * 512] = 0;
        __syncthreads();

        for (int k = t; k < len; k += 512) {
            const int idx = start + k;
            const int r = rows[idx];
            const int c = cols[idx];
            const float v = vals[idx];
            const float gv = v * (idx < NEDGE ? g0 : (idx < 2 * NEDGE ? g1 : g2));
            uint2 rec;
            rec.x = ((unsigned)r << 16) | (unsigned)c;
            rec.y = __float_as_uint(gv);
            stg[k] = rec;
            rnk[k] = (unsigned short)atomicAdd(&sA[bucket_of((unsigned)r)], 1);
        }
        __syncthreads();

        for (int off = 1; off < 1536; off <<= 1) {
            int v[3];
#pragma unroll
            for (int j = 0; j < 3; ++j) {
                const int i = t + j * 512;
                v[j] = sA[i] + ((i >= off) ? sA[i - off] : 0);
            }
            __syncthreads();
#pragma unroll
            for (int j = 0; j < 3; ++j) sA[t + j * 512] = v[j];
            __syncthreads();
        }

        if (t < NBUK) off1[(size_t)bb * OS + t] = (unsigned short)(t ? sA[t - 1] : 0);
        for (int b = t + 512; b < NBUK; b += 512)
            off1[(size_t)bb * OS + b] = (unsigned short)sA[b - 1];
        if (t == 0) off1[(size_t)bb * OS + NBUK] = (unsigned short)sA[NBUK - 1];

        for (int k = t; k < len; k += 512) {
            const uint2 rec = stg[k];
            const int b = bucket_of(rec.x >> 16);
            const int pos = (b ? sA[b - 1] : 0) + (int)rnk[k];
            out1[(size_t)bb * CH + pos] = rec;
        }
    }
}

// ---------------------------------------------------------------------------
// K_AGG with COL-PHASE L2 WINDOWING. Records per bucket sorted by
// (phase = col>>13, row): P4 walks phase-major, so all waves of all blocks
// gather from the same 2MB hbits window (8192 cols x 256B) at the same time
// -> window stays L2-resident per XCD, ~5x ref/col within a residence.
// Wave accumulators for its 4-5 rows live in registers across all phases
// (unrolled, compile-time indexed). Groups pad to 4 (col=0,val=0: inert).
// Predicted: gather L2-fill 220MB -> ~102MB; FETCH 308 -> ~190MB.
// ---------------------------------------------------------------------------
__global__ __launch_bounds__(512, 8) void k_agg(const unsigned* __restrict__ hbits,
                                                const uint2* __restrict__ out1,
                                                const unsigned short* __restrict__ off1,
                                                float* __restrict__ out) {
    __shared__ __align__(16) uint2          stg[STGCAP];   // 15,360 B
    __shared__ __align__(16) unsigned short colS[SCAP];    //  5,248 B
    __shared__ __align__(16) float          valS[SCAP];    // 10,496 B
    __shared__ int rh[MAXG], grpBase[MAXG + 1], gcur[MAXG];
    __shared__ int sA[512];
    const int t = threadIdx.x;
    const int b = blockIdx.x;

    // bucket row range: [ceil(b*3125/96), ceil((b+1)*3125/96))
    const int sstart = (b * 3125 + 95) / 96;
    const int send   = ((b + 1) * 3125 + 95) / 96;
    const int width  = send - sstart;                      // 32 or 33
    const int ngrp   = NPH * width;                        // 224 or 231

    if (t < MAXG) rh[t] = 0;

    // exactly one segment per thread
    const int s0 = off1[(size_t)t * OS + b];
    const int e0 = off1[(size_t)t * OS + b + 1];
    const int len = e0 - s0;
    sA[t] = len;
    __syncthreads();

    // 512-wide inclusive scan -> per-thread staging base
    for (int off = 1; off < 512; off <<= 1) {
        const int v = sA[t] + ((t >= off) ? sA[t - off] : 0);
        __syncthreads();
        sA[t] = v;
        __syncthreads();
    }
    const int base = sA[t] - len;
    __syncthreads();   // sA reused below

    // P1: single global read; stage + per-(phase,row) histogram
    {
        const uint2* seg = out1 + (size_t)t * CH;
        int p = base;
        for (int i = s0; i < e0; ++i, ++p) {
            const uint2 rec = seg[i];
            if (p < STGCAP) {
                stg[p] = rec;
                const int lr = (int)(rec.x >> 16) - sstart;
                const int ph = (int)((rec.x & 0xffffu) >> 13);
                atomicAdd(&rh[ph * width + lr], 1);
            }
        }
    }
    __syncthreads();

    // P2: scan of 4-padded group counts -> 4-aligned group bases + pad fill
    if (t < 256) sA[t] = (t < ngrp) ? ((rh[t] + 3) & ~3) : 0;
    __syncthreads();
    for (int off = 1; off < 256; off <<= 1) {
        int v = 0;
        if (t < 256) v = sA[t] + ((t >= off) ? sA[t - off] : 0);
        __syncthreads();
        if (t < 256) sA[t] = v;
        __syncthreads();
    }
    if (t < ngrp) {
        const int pc = (rh[t] + 3) & ~3;
        const int gb = sA[t] - pc;
        grpBase[t] = gb;
        gcur[t]    = gb;
        for (int k = gb + rh[t]; k < gb + pc; ++k) { colS[k] = 0; valS[k] = 0.f; }
    }
    if (t == 0) grpBase[MAXG] = 0;   // unused slot; real total below
    if (t == 256 - 1) { /* nothing */ }
    __syncthreads();
    if (t == 0) grpBase[ngrp] = sA[ngrp - 1];
    __syncthreads();

    // P3: LDS->LDS scatter straight into (phase,row)-sorted position
    {
        const int lim = (base + len < STGCAP) ? (base + len) : STGCAP;
        for (int k = base; k < lim; ++k) {
            const uint2 rec = stg[k];
            const int lr = (int)(rec.x >> 16) - sstart;
            const int ph = (int)((rec.x & 0xffffu) >> 13);
            const int pos = atomicAdd(&gcur[ph * width + lr], 1);
            colS[pos] = (unsigned short)(rec.x & 0xffffu);
            valS[pos] = __uint_as_float(rec.y);
        }
    }
    __syncthreads();

    // P4: phase-major gather. Wave w owns rows lr = w+8*ri (ri<5), acc in regs.
    const int w    = t >> 6;
    const int lane = t & 63;
    float2 acc[5];
#pragma unroll
    for (int ri = 0; ri < 5; ++ri) acc[ri] = make_float2(0.f, 0.f);

    for (int ph = 0; ph < NPH; ++ph) {
#pragma unroll
        for (int ri = 0; ri < 5; ++ri) {
            const int lr = w + ri * 8;
            if (lr < width) {
                const int g = ph * width + lr;
                const int s = grpBase[g];
                const int e = grpBase[g + 1];
                int i = s;
                for (; i + 8 <= e; i += 8) {
                    const uint2  ca = *(const uint2*)&colS[i];
                    const uint2  cb = *(const uint2*)&colS[i + 4];
                    const float4 v0 = *(const float4*)&valS[i];
                    const float4 v1 = *(const float4*)&valS[i + 4];
                    unsigned hb[8];
                    hb[0] = hbits[(size_t)(ca.x & 0xffffu) * 64 + lane];
                    hb[1] = hbits[(size_t)(ca.x >> 16)     * 64 + lane];
                    hb[2] = hbits[(size_t)(ca.y & 0xffffu) * 64 + lane];
                    hb[3] = hbits[(size_t)(ca.y >> 16)     * 64 + lane];
                    hb[4] = hbits[(size_t)(cb.x & 0xffffu) * 64 + lane];
                    hb[5] = hbits[(size_t)(cb.x >> 16)     * 64 + lane];
                    hb[6] = hbits[(size_t)(cb.y & 0xffffu) * 64 + lane];
                    hb[7] = hbits[(size_t)(cb.y >> 16)     * 64 + lane];
                    const float vv[8] = {v0.x, v0.y, v0.z, v0.w, v1.x, v1.y, v1.z, v1.w};
#pragma unroll
                    for (int j = 0; j < 8; ++j) {
                        acc[ri].x += vv[j] * __uint_as_float(hb[j] << 16);
                        acc[ri].y += vv[j] * __uint_as_float(hb[j] & 0xffff0000u);
                    }
                }
                if (i < e) {   // exactly one 4-wide remainder (padded to 4)
                    const uint2  ca = *(const uint2*)&colS[i];
                    const float4 v0 = *(const float4*)&valS[i];
                    unsigned hb[4];
                    hb[0] = hbits[(size_t)(ca.x & 0xffffu) * 64 + lane];
                    hb[1] = hbits[(size_t)(ca.x >> 16)     * 64 + lane];
                    hb[2] = hbits[(size_t)(ca.y & 0xffffu) * 64 + lane];
                    hb[3] = hbits[(size_t)(ca.y >> 16)     * 64 + lane];
                    const float vv[4] = {v0.x, v0.y, v0.z, v0.w};
#pragma unroll
                    for (int j = 0; j < 4; ++j) {
                        acc[ri].x += vv[j] * __uint_as_float(hb[j] << 16);
                        acc[ri].y += vv[j] * __uint_as_float(hb[j] & 0xffff0000u);
                    }
                }
            }
        }
    }

#pragma unroll
    for (int ri = 0; ri < 5; ++ri) {
        const int lr = w + ri * 8;
        if (lr < width) {
            const int row = sstart + lr;
            ((float2*)out)[(size_t)row * 64 + lane] = acc[ri];
        }
    }
}

extern "C" void kernel_launch(void* const* d_in, const int* in_sizes, int n_in,
                              void* d_out, int out_size, void* d_ws, size_t ws_size,
                              hipStream_t stream) {
    const float* X     = (const float*)d_in[0];
    const float* W     = (const float*)d_in[1];
    const float* alpha = (const float*)d_in[2];
    const int*   rows  = (const int*)d_in[3];
    const int*   cols  = (const int*)d_in[4];
    const float* vals  = (const float*)d_in[5];
    float* out = (float*)d_out;

    // workspace layout (<= 33,870,176 B proven footprint)
    char* ws = (char*)d_ws;
    unsigned*       hbits = (unsigned*)(ws + 0);              // 12,800,000 B
    unsigned short* hb16  = (unsigned short*)(ws + 0);        // same bytes, u16 view
    uint2*          out1  = (uint2*)(ws + 12800000);          // 512*4688*8 = 19,202,048 B
    unsigned short* off1  = (unsigned short*)(ws + 32002048); // 512*1537*2 =  1,573,888 B
    // total: 33,575,936 B

    hipLaunchKernelGGL(k_front, dim3(FGRID), dim3(512), 0, stream,
                       X, W, rows, cols, vals, alpha, hb16, out1, off1);
    hipLaunchKernelGGL(k_agg, dim3(NBUK), dim3(512), 0, stream,
                       hbits, out1, off1, out);
}

// Round 5
// 212.508 us; speedup vs baseline: 1.2105x; 1.0014x over previous
//
#include <hip/hip_runtime.h>
#include <math.h>

#define NNODES 50000
#define NEDGE  800000
#define NG     3
#define GE     (NG*NEDGE)            // 2,400,000 combined edges
#define NBUK   2048                  // row buckets: bucket(r) = r*128/3125 -> 24/25 rows each
#define OS     (NBUK + 1)            // 2049, off1 row stride
#define CH     6000                  // edges per bin block; 400*6000 == GE exactly
#define NBLK   400                   // bin blocks (< 512: one segment per k_agg thread)
#define GBLK   391                   // gemm sub-grid blocks of 128 rows (391*128 = 50048)
#define FGRID  (GBLK + NBLK)         // 791 fused front blocks <= 1024 slots: SINGLE pass
#define STGCAP 1536                  // raw record cap per bucket (mean 1172, sigma 34; +10.7 sigma)
#define NPH    7                     // col phases: col>>13 -> 8192-col windows (2MB of hbits each)
#define MAXG   175                   // max groups = NPH * 25
#define SCAP   2112                  // sorted cap: STGCAP + MAXG*3 = 2061 -> never overflows

typedef __attribute__((ext_vector_type(8))) short bf16x8;
typedef __attribute__((ext_vector_type(4))) float f32x4;

// fp32 -> bf16 round-to-nearest-even (no NaN inputs here)
__device__ __forceinline__ unsigned short f2bf(float f) {
    unsigned u = __float_as_uint(f);
    return (unsigned short)((u + 0x7fffu + ((u >> 16) & 1u)) >> 16);
}

// bucket of row r: floor(r*2048/50000) = floor(r*128/3125); exact for r < 50000
__device__ __forceinline__ int bucket_of(unsigned r) {
    return (int)((r * 128u) / 3125u);
}

// ---------------------------------------------------------------------------
// K_FRONT: fused {W-swizzle + GEMM} | {edge binning}.
// r5 quantization fix: LDS cut to 34,816B (gemm transpose union; bin now only
// 20.2KB after dropping stg[] -- pass 2 re-reads the contiguous, L2-hot edge
// streams instead) -> 4 blocks/CU -> 1024 slots >= 791 blocks = ONE pass
// (was 3/CU, 903/768 = 1.18 passes + 24 waves/CU).
// ---------------------------------------------------------------------------
__global__ __launch_bounds__(512) void k_front(const float* __restrict__ X,
                                               const float* __restrict__ W,
                                               const int* __restrict__ rows,
                                               const int* __restrict__ cols,
                                               const float* __restrict__ vals,
                                               const float* __restrict__ alpha,
                                               unsigned short* __restrict__ hb16,
                                               uint2* __restrict__ out1,
                                               unsigned short* __restrict__ off1) {
    __shared__ __align__(16) char smem[34816];
    const int t = threadIdx.x;

    if (blockIdx.x < GBLK) {
        // ---------------- GEMM path ----------------
        uint4* Wl = (uint4*)smem;   // 2048 records = 32KB
        for (int i = t; i < 2048; i += 512) {
            const int nt   = i >> 8;
            const int kc   = (i >> 6) & 3;
            const int lane = i & 63;
            const int n  = nt * 16 + (lane & 15);
            const int k0 = kc * 32 + (lane >> 4) * 8;
            const float* src = W + (size_t)n * 128 + k0;
            float4 a = *(const float4*)(src);
            float4 b = *(const float4*)(src + 4);
            unsigned u0 = (unsigned)f2bf(a.x) | ((unsigned)f2bf(a.y) << 16);
            unsigned u1 = (unsigned)f2bf(a.z) | ((unsigned)f2bf(a.w) << 16);
            unsigned u2 = (unsigned)f2bf(b.x) | ((unsigned)f2bf(b.y) << 16);
            unsigned u3 = (unsigned)f2bf(b.z) | ((unsigned)f2bf(b.w) << 16);
            Wl[i] = make_uint4(u0, u1, u2, u3);
        }
        __syncthreads();

        const int w    = t >> 6;
        const int lane = t & 63;
        const int q    = lane >> 4;
        const int ml   = lane & 15;
        const int m0   = blockIdx.x * 128 + w * 16;

        int xr = m0 + ml; if (xr >= NNODES) xr = NNODES - 1;
        const float* xrow = X + (size_t)xr * 128;

        bf16x8 xf[4];
#pragma unroll
        for (int kc = 0; kc < 4; ++kc) {
            const int k0 = kc * 32 + q * 8;
            float4 a = *(const float4*)(xrow + k0);
            float4 b = *(const float4*)(xrow + k0 + 4);
            bf16x8 v;
            v[0] = (short)f2bf(a.x); v[1] = (short)f2bf(a.y);
            v[2] = (short)f2bf(a.z); v[3] = (short)f2bf(a.w);
            v[4] = (short)f2bf(b.x); v[5] = (short)f2bf(b.y);
            v[6] = (short)f2bf(b.z); v[7] = (short)f2bf(b.w);
            xf[kc] = v;
        }

        f32x4 acc[8];
#pragma unroll
        for (int nt = 0; nt < 8; ++nt) acc[nt] = (f32x4){0.f, 0.f, 0.f, 0.f};
#pragma unroll
        for (int nt = 0; nt < 8; ++nt)
#pragma unroll
            for (int kc = 0; kc < 4; ++kc) {
                const bf16x8 wf = *(const bf16x8*)&Wl[(nt * 4 + kc) * 64 + lane];
                acc[nt] = __builtin_amdgcn_mfma_f32_16x16x32_bf16(xf[kc], wf, acc[nt], 0, 0, 0);
            }
        __syncthreads();   // done reading Wl; reuse region for transpose

        // per-wave 16x128 u16 tile, row stride 136 u16 (16B-aligned, banks spread)
        unsigned short* hst = (unsigned short*)smem + w * 2176;
#pragma unroll
        for (int nt = 0; nt < 8; ++nt)
#pragma unroll
            for (int r = 0; r < 4; ++r)
                hst[(q * 4 + r) * 136 + nt * 16 + ml] = f2bf(acc[nt][r]);
        __syncthreads();

#pragma unroll
        for (int i = 0; i < 4; ++i) {
            const int chunk = i * 64 + lane;
            const int lr    = chunk >> 4;
            const int cc    = chunk & 15;
            const int row   = m0 + lr;
            const uint4 v = *(const uint4*)(hst + lr * 136 + cc * 8);
            if (row < NNODES)
                ((uint4*)(hb16 + (size_t)row * 128))[cc] = v;
        }
    } else {
        // ---------------- BIN path (stg[] dropped; 20.2KB LDS) ----------------
        unsigned short* rnk = (unsigned short*)smem;         // 12,000 B
        int*            sA  = (int*)(smem + 12032);          //  8,192 B
        const int bb    = blockIdx.x - GBLK;
        const int start = bb * CH;                           // end = start+CH (exact fit)

        const float g0 = 1.0f / (1.0f + __expf(-alpha[0]));
        const float g1 = 1.0f / (1.0f + __expf(-alpha[1]));
        const float g2 = 1.0f / (1.0f + __expf(-alpha[2]));

#pragma unroll
        for (int j = 0; j < 4; ++j) sA[t + j * 512] = 0;
        __syncthreads();

        // pass 1: histogram + rank (rows stream only)
        for (int k = t; k < CH; k += 512) {
            const int r = rows[start + k];
            rnk[k] = (unsigned short)atomicAdd(&sA[bucket_of((unsigned)r)], 1);
        }
        __syncthreads();

        // in-place inclusive scan over 2048 (11 steps)
        for (int off = 1; off < 2048; off <<= 1) {
            int v[4];
#pragma unroll
            for (int j = 0; j < 4; ++j) {
                const int i = t + j * 512;
                v[j] = sA[i] + ((i >= off) ? sA[i - off] : 0);
            }
            __syncthreads();
#pragma unroll
            for (int j = 0; j < 4; ++j) sA[t + j * 512] = v[j];
            __syncthreads();
        }

        // off1 = exclusive offsets (values <= 6000 -> u16)
        for (int b = t; b < NBUK; b += 512)
            off1[(size_t)bb * OS + b] = (unsigned short)(b ? sA[b - 1] : 0);
        if (t == 0) off1[(size_t)bb * OS + NBUK] = (unsigned short)sA[NBUK - 1];

        // pass 2: re-read edge streams (contiguous, L2-hot), scatter to out1
        for (int k = t; k < CH; k += 512) {
            const int idx = start + k;
            const int r = rows[idx];
            const int c = cols[idx];
            const float v = vals[idx];
            const float gv = v * (idx < NEDGE ? g0 : (idx < 2 * NEDGE ? g1 : g2));
            const int b = bucket_of((unsigned)r);
            const int pos = (b ? sA[b - 1] : 0) + (int)rnk[k];
            uint2 rec;
            rec.x = ((unsigned)r << 16) | (unsigned)c;
            rec.y = __float_as_uint(gv);
            out1[(size_t)bb * CH + pos] = rec;
        }
    }
}

// ---------------------------------------------------------------------------
// K_AGG: one block (512 thr = 8 waves) per 24/25-row bucket, phase-sorted
// gather (r4 structure). r5 quantization fix: 2048 blocks at 4 blocks/CU
// (LDS 29.5KB) = EXACTLY 2 full passes (was 1536/1024 = 1.5 passes -> 25%
// makespan tail, Occupancy stuck at 62%).
// ---------------------------------------------------------------------------
__global__ __launch_bounds__(512, 8) void k_agg(const unsigned* __restrict__ hbits,
                                                const uint2* __restrict__ out1,
                                                const unsigned short* __restrict__ off1,
                                                float* __restrict__ out) {
    __shared__ __align__(16) uint2          stg[STGCAP];   // 12,288 B
    __shared__ __align__(16) unsigned short colS[SCAP];    //  4,224 B
    __shared__ __align__(16) float          valS[SCAP];    //  8,448 B
    __shared__ int rh[MAXG], grpBase[MAXG + 1], gcur[MAXG];
    __shared__ int sA[512];
    const int t = threadIdx.x;
    const int b = blockIdx.x;

    // bucket row range: [ceil(b*3125/128), ceil((b+1)*3125/128))
    const int sstart = (b * 3125 + 127) >> 7;
    const int send   = ((b + 1) * 3125 + 127) >> 7;
    const int width  = send - sstart;                      // 24 or 25
    const int ngrp   = NPH * width;                        // 168 or 175

    if (t < MAXG) rh[t] = 0;

    // one segment per thread (threads >= NBLK idle here)
    int s0 = 0, e0 = 0;
    if (t < NBLK) {
        s0 = off1[(size_t)t * OS + b];
        e0 = off1[(size_t)t * OS + b + 1];
    }
    const int len = e0 - s0;
    sA[t] = len;
    __syncthreads();

    // 512-wide inclusive scan -> per-thread staging base
    for (int off = 1; off < 512; off <<= 1) {
        const int v = sA[t] + ((t >= off) ? sA[t - off] : 0);
        __syncthreads();
        sA[t] = v;
        __syncthreads();
    }
    const int base = sA[t] - len;
    __syncthreads();   // sA reused below

    // P1: single global read; stage + per-(phase,row) histogram
    {
        const uint2* seg = out1 + (size_t)t * CH;
        int p = base;
        for (int i = s0; i < e0; ++i, ++p) {
            const uint2 rec = seg[i];
            if (p < STGCAP) {
                stg[p] = rec;
                const int lr = (int)(rec.x >> 16) - sstart;
                const int ph = (int)((rec.x & 0xffffu) >> 13);
                atomicAdd(&rh[ph * width + lr], 1);
            }
        }
    }
    __syncthreads();

    // P2: scan of 4-padded group counts -> 4-aligned group bases + pad fill
    if (t < 256) sA[t] = (t < ngrp) ? ((rh[t] + 3) & ~3) : 0;
    __syncthreads();
    for (int off = 1; off < 256; off <<= 1) {
        int v = 0;
        if (t < 256) v = sA[t] + ((t >= off) ? sA[t - off] : 0);
        __syncthreads();
        if (t < 256) sA[t] = v;
        __syncthreads();
    }
    if (t < ngrp) {
        const int pc = (rh[t] + 3) & ~3;
        const int gb = sA[t] - pc;
        grpBase[t] = gb;
        gcur[t]    = gb;
        for (int k = gb + rh[t]; k < gb + pc; ++k) { colS[k] = 0; valS[k] = 0.f; }
    }
    __syncthreads();
    if (t == 0) grpBase[ngrp] = sA[ngrp - 1];
    __syncthreads();

    // P3: LDS->LDS scatter straight into (phase,row)-sorted position
    {
        const int lim = (base + len < STGCAP) ? (base + len) : STGCAP;
        for (int k = base; k < lim; ++k) {
            const uint2 rec = stg[k];
            const int lr = (int)(rec.x >> 16) - sstart;
            const int ph = (int)((rec.x & 0xffffu) >> 13);
            const int pos = atomicAdd(&gcur[ph * width + lr], 1);
            colS[pos] = (unsigned short)(rec.x & 0xffffu);
            valS[pos] = __uint_as_float(rec.y);
        }
    }
    __syncthreads();

    // P4: phase-major gather. Wave w owns rows lr = w+8*ri (ri<4), acc in regs.
    const int w    = t >> 6;
    const int lane = t & 63;
    float2 acc[4];
#pragma unroll
    for (int ri = 0; ri < 4; ++ri) acc[ri] = make_float2(0.f, 0.f);

    for (int ph = 0; ph < NPH; ++ph) {
#pragma unroll
        for (int ri = 0; ri < 4; ++ri) {
            const int lr = w + ri * 8;
            if (lr < width) {
                const int g = ph * width + lr;
                const int s = grpBase[g];
                const int e = grpBase[g + 1];
                int i = s;
                for (; i + 8 <= e; i += 8) {
                    const uint2  ca = *(const uint2*)&colS[i];
                    const uint2  cb = *(const uint2*)&colS[i + 4];
                    const float4 v0 = *(const float4*)&valS[i];
                    const float4 v1 = *(const float4*)&valS[i + 4];
                    unsigned hb[8];
                    hb[0] = hbits[(size_t)(ca.x & 0xffffu) * 64 + lane];
                    hb[1] = hbits[(size_t)(ca.x >> 16)     * 64 + lane];
                    hb[2] = hbits[(size_t)(ca.y & 0xffffu) * 64 + lane];
                    hb[3] = hbits[(size_t)(ca.y >> 16)     * 64 + lane];
                    hb[4] = hbits[(size_t)(cb.x & 0xffffu) * 64 + lane];
                    hb[5] = hbits[(size_t)(cb.x >> 16)     * 64 + lane];
                    hb[6] = hbits[(size_t)(cb.y & 0xffffu) * 64 + lane];
                    hb[7] = hbits[(size_t)(cb.y >> 16)     * 64 + lane];
                    const float vv[8] = {v0.x, v0.y, v0.z, v0.w, v1.x, v1.y, v1.z, v1.w};
#pragma unroll
                    for (int j = 0; j < 8; ++j) {
                        acc[ri].x += vv[j] * __uint_as_float(hb[j] << 16);
                        acc[ri].y += vv[j] * __uint_as_float(hb[j] & 0xffff0000u);
                    }
                }
                if (i < e) {   // exactly one 4-wide remainder (padded to 4)
                    const uint2  ca = *(const uint2*)&colS[i];
                    const float4 v0 = *(const float4*)&valS[i];
                    unsigned hb[4];
                    hb[0] = hbits[(size_t)(ca.x & 0xffffu) * 64 + lane];
                    hb[1] = hbits[(size_t)(ca.x >> 16)     * 64 + lane];
                    hb[2] = hbits[(size_t)(ca.y & 0xffffu) * 64 + lane];
                    hb[3] = hbits[(size_t)(ca.y >> 16)     * 64 + lane];
                    const float vv[4] = {v0.x, v0.y, v0.z, v0.w};
#pragma unroll
                    for (int j = 0; j < 4; ++j) {
                        acc[ri].x += vv[j] * __uint_as_float(hb[j] << 16);
                        acc[ri].y += vv[j] * __uint_as_float(hb[j] & 0xffff0000u);
                    }
                }
            }
        }
    }

#pragma unroll
    for (int ri = 0; ri < 4; ++ri) {
        const int lr = w + ri * 8;
        if (lr < width) {
            const int row = sstart + lr;
            ((float2*)out)[(size_t)row * 64 + lane] = acc[ri];
        }
    }
}

extern "C" void kernel_launch(void* const* d_in, const int* in_sizes, int n_in,
                              void* d_out, int out_size, void* d_ws, size_t ws_size,
                              hipStream_t stream) {
    const float* X     = (const float*)d_in[0];
    const float* W     = (const float*)d_in[1];
    const float* alpha = (const float*)d_in[2];
    const int*   rows  = (const int*)d_in[3];
    const int*   cols  = (const int*)d_in[4];
    const float* vals  = (const float*)d_in[5];
    float* out = (float*)d_out;

    // workspace layout (33,639,200 B <= 33,870,176 proven footprint)
    char* ws = (char*)d_ws;
    unsigned*       hbits = (unsigned*)(ws + 0);              // 12,800,000 B
    unsigned short* hb16  = (unsigned short*)(ws + 0);        // same bytes, u16 view
    uint2*          out1  = (uint2*)(ws + 12800000);          // 400*6000*8 = 19,200,000 B
    unsigned short* off1  = (unsigned short*)(ws + 32000000); // 400*2049*2 =  1,639,200 B

    hipLaunchKernelGGL(k_front, dim3(FGRID), dim3(512), 0, stream,
                       X, W, rows, cols, vals, alpha, hb16, out1, off1);
    hipLaunchKernelGGL(k_agg, dim3(NBUK), dim3(512), 0, stream,
                       hbits, out1, off1, out);
}